// Round 1
// baseline (17.239 us; speedup 1.0000x reference)
//
#include <hip/hip_runtime.h>

#define NG 2048
#define WIMG 256
#define HIMG 256
#define TILE 16
#define CAP 1280
#define LOG2E 1.4426950408889634f
#define LOG2EPS -23.25f   // 2^-23.25 ~ 1e-7 : per-gaussian skip epsilon

__device__ __forceinline__ float sigmoidf_(float x) {
    return 1.0f / (1.0f + __expf(-x));
}

__global__ __launch_bounds__(256) void GaussianImage_render_kernel(
    const float* __restrict__ xyz,      // (3, N, 2)
    const float* __restrict__ chol,     // (3, N, 3)
    const float* __restrict__ opacity,  // (N, 1)
    const float* __restrict__ feat,     // (N, 3)
    const int*   __restrict__ fidx,     // scalar frame index
    float*       __restrict__ out)      // (1, 3, H, W)
{
    // survivor list in LDS: 9 params packed as float4+float4+float
    __shared__ float4 sP[CAP];   // cx, cy, na, nb
    __shared__ float4 sQ[CAP];   // nc, k,  cr, cg
    __shared__ float  sB[CAP];   // cb
    __shared__ int    swcnt[4];

    const int tid  = threadIdx.x;
    const int lane = tid & 63;
    const int wid  = tid >> 6;
    const int bx   = blockIdx.x & 15;
    const int by   = blockIdx.x >> 4;
    const int ix   = bx * TILE + (tid & 15);
    const int iy   = by * TILE + (tid >> 4);
    const float px = (float)ix + 0.5f;
    const float py = (float)iy + 0.5f;
    const float tx0 = (float)(bx * TILE);
    const float ty0 = (float)(by * TILE);

    const float t  = (float)(*fidx) * (1.0f / 7.0f);   // linspace(0,1,8)[i]
    const float t2 = t * t;

    float accR = 0.0f, accG = 0.0f, accB = 0.0f;
    int cnt = 0;

    // inner render pass over the compacted survivor list
    auto render = [&](int n) {
#pragma unroll 2
        for (int s = 0; s < n; ++s) {
            float4 P = sP[s];
            float4 Q = sQ[s];
            float  cb = sB[s];
            float dx = px - P.x;
            float dy = py - P.y;
            // arg = log2(opac) - log2(e)*sigma   (all folded at prep time)
            float arg = fmaf(P.z, dx * dx,
                        fmaf(P.w, dx * dy,
                        fmaf(Q.x, dy * dy, Q.y)));
            float e = __builtin_amdgcn_exp2f(arg);
            float a = fminf(e, 0.99f);
            accR = fmaf(a, Q.z, accR);
            accG = fmaf(a, Q.w, accG);
            accB = fmaf(a, cb, accB);
        }
    };

    const float2* xy2 = (const float2*)xyz;

    for (int c = 0; c < NG / 256; ++c) {
        const int g = c * 256 + tid;

        // ---- per-gaussian prep (each thread owns one gaussian) ----
        float2 a0 = xy2[0 * NG + g];
        float2 a1 = xy2[1 * NG + g];
        float2 a2 = xy2[2 * NG + g];
        float mx = tanhf(fmaf(t2, a2.x, fmaf(t, a1.x, a0.x)));
        float my = tanhf(fmaf(t2, a2.y, fmaf(t, a1.y, a0.y)));
        float cx = 128.0f * (mx + 1.0f);
        float cy = 128.0f * (my + 1.0f);

        const float* c0 = chol + g * 3;
        float l1 = fmaf(t2, c0[2 * NG * 3 + 0], fmaf(t, c0[NG * 3 + 0], c0[0])) + 0.5f;
        float l2 = fmaf(t2, c0[2 * NG * 3 + 1], fmaf(t, c0[NG * 3 + 1], c0[1]));
        float l3 = fmaf(t2, c0[2 * NG * 3 + 2], fmaf(t, c0[NG * 3 + 2], c0[2])) + 0.5f;

        float s11 = l1 * l1;
        float s12 = l1 * l2;
        float s22 = fmaf(l2, l2, l3 * l3);
        float det = fmaf(s11, s22, -s12 * s12);
        float rdet = __builtin_amdgcn_rcpf(det);
        float A =  s22 * rdet;
        float B = -s12 * rdet;
        float C =  s11 * rdet;

        float opac = sigmoidf_(opacity[g]);
        float k  = __builtin_amdgcn_logf(opac);      // log2(opac)
        float na = -0.5f * LOG2E * A;
        float nb = -LOG2E * B;
        float nc = -0.5f * LOG2E * C;

        float cr = sigmoidf_(feat[g * 3 + 0]);
        float cg = sigmoidf_(feat[g * 3 + 1]);
        float cb = sigmoidf_(feat[g * 3 + 2]);

        // ---- conservative tile cull: sigma >= 0.5*lambda_min*d^2 ----
        float dxt = fmaxf(fmaxf(tx0 - cx, cx - (tx0 + (float)TILE)), 0.0f);
        float dyt = fmaxf(fmaxf(ty0 - cy, cy - (ty0 + (float)TILE)), 0.0f);
        float d2  = fmaf(dxt, dxt, dyt * dyt);
        float amc = A - C;
        float lm  = 0.5f * (A + C) - sqrtf(fmaf(0.25f * amc, amc, B * B));
        float bnd = fmaf(-0.5f * LOG2E * lm, d2, k);
        bool  drop = (lm > 0.0f) && (bnd < LOG2EPS);  // NaN-safe: keeps on NaN
        bool  keep = !drop;

        // ---- flush if the list could overflow (never hits for this data) ----
        if (cnt + 256 > CAP) {
            render(cnt);
            __syncthreads();
            cnt = 0;
        }

        // ---- deterministic ballot compaction ----
        unsigned long long m = __ballot(keep);
        if (lane == 0) swcnt[wid] = __popcll(m);
        __syncthreads();
        int base = cnt;
#pragma unroll
        for (int w = 0; w < 4; ++w)
            if (w < wid) base += swcnt[w];
        int total = swcnt[0] + swcnt[1] + swcnt[2] + swcnt[3];
        if (keep) {
            int idx = base + __popcll(m & ((1ULL << lane) - 1ULL));
            sP[idx] = make_float4(cx, cy, na, nb);
            sQ[idx] = make_float4(nc, k, cr, cg);
            sB[idx] = cb;
        }
        cnt += total;
        __syncthreads();   // list writes visible; swcnt reusable
    }

    render(cnt);

    const int pix = iy * WIMG + ix;
    out[pix]                   = fminf(fmaxf(accR, 0.0f), 1.0f);
    out[HIMG * WIMG + pix]     = fminf(fmaxf(accG, 0.0f), 1.0f);
    out[2 * HIMG * WIMG + pix] = fminf(fmaxf(accB, 0.0f), 1.0f);
}

extern "C" void kernel_launch(void* const* d_in, const int* in_sizes, int n_in,
                              void* d_out, int out_size, void* d_ws, size_t ws_size,
                              hipStream_t stream) {
    const float* xyz     = (const float*)d_in[0];
    const float* chol    = (const float*)d_in[1];
    const float* opacity = (const float*)d_in[2];
    const float* feat    = (const float*)d_in[3];
    const int*   fidx    = (const int*)d_in[4];
    float*       out     = (float*)d_out;

    hipLaunchKernelGGL(GaussianImage_render_kernel,
                       dim3((WIMG / TILE) * (HIMG / TILE)), dim3(TILE * TILE),
                       0, stream,
                       xyz, chol, opacity, feat, fidx, out);
}